// Round 2
// baseline (1304.670 us; speedup 1.0000x reference)
//
#include <hip/hip_runtime.h>

#define HID 1024
#define HEADS 16
#define HD 64
#define TAB 129
#define BATCH 8
#define SEQ 512

typedef unsigned int uint;
typedef unsigned short ushort;

// ---------------------------------------------------------------------------
// C[M,N] = A[M,K] @ W[N,K]^T + bias[N]   (both operands row-major, "NT" gemm)
// 128x128 tile, BK=16, 256 threads, 8x8 per thread, fp32.  (unchanged R0)
// ---------------------------------------------------------------------------
__global__ __launch_bounds__(256) void gemm_nt_bias(const float* __restrict__ A,
                                                    const float* __restrict__ W,
                                                    const float* __restrict__ bias,
                                                    float* __restrict__ C,
                                                    int M, int N, int K) {
    __shared__ float As[16][132];
    __shared__ float Ws[16][132];
    const int tid = threadIdx.x;
    const int m0 = blockIdx.y * 128;
    const int n0 = blockIdx.x * 128;
    const int tx = tid & 15;
    const int ty = tid >> 4;
    const int lr = tid >> 2;
    const int lk = (tid & 3) << 2;

    float acc[8][8];
#pragma unroll
    for (int i = 0; i < 8; ++i)
#pragma unroll
        for (int j = 0; j < 8; ++j) acc[i][j] = 0.f;

    const float* Arow0 = A + (size_t)(m0 + lr) * K + lk;
    const float* Arow1 = A + (size_t)(m0 + lr + 64) * K + lk;
    const float* Wrow0 = W + (size_t)(n0 + lr) * K + lk;
    const float* Wrow1 = W + (size_t)(n0 + lr + 64) * K + lk;

    for (int k0 = 0; k0 < K; k0 += 16) {
        float4 a0 = *(const float4*)(Arow0 + k0);
        float4 a1 = *(const float4*)(Arow1 + k0);
        float4 w0 = *(const float4*)(Wrow0 + k0);
        float4 w1 = *(const float4*)(Wrow1 + k0);
        __syncthreads();
        As[lk+0][lr]    = a0.x; As[lk+1][lr]    = a0.y; As[lk+2][lr]    = a0.z; As[lk+3][lr]    = a0.w;
        As[lk+0][lr+64] = a1.x; As[lk+1][lr+64] = a1.y; As[lk+2][lr+64] = a1.z; As[lk+3][lr+64] = a1.w;
        Ws[lk+0][lr]    = w0.x; Ws[lk+1][lr]    = w0.y; Ws[lk+2][lr]    = w0.z; Ws[lk+3][lr]    = w0.w;
        Ws[lk+0][lr+64] = w1.x; Ws[lk+1][lr+64] = w1.y; Ws[lk+2][lr+64] = w1.z; Ws[lk+3][lr+64] = w1.w;
        __syncthreads();
#pragma unroll
        for (int kk = 0; kk < 16; ++kk) {
            float4 av0 = *(const float4*)&As[kk][ty*8];
            float4 av1 = *(const float4*)&As[kk][ty*8+4];
            float4 wv0 = *(const float4*)&Ws[kk][tx*8];
            float4 wv1 = *(const float4*)&Ws[kk][tx*8+4];
            float am[8] = {av0.x, av0.y, av0.z, av0.w, av1.x, av1.y, av1.z, av1.w};
            float wn[8] = {wv0.x, wv0.y, wv0.z, wv0.w, wv1.x, wv1.y, wv1.z, wv1.w};
#pragma unroll
            for (int i = 0; i < 8; ++i)
#pragma unroll
                for (int j = 0; j < 8; ++j)
                    acc[i][j] = fmaf(am[i], wn[j], acc[i][j]);
        }
    }
#pragma unroll
    for (int i = 0; i < 8; ++i) {
        int m = m0 + ty*8 + i;
#pragma unroll
        for (int jj = 0; jj < 2; ++jj) {
            int n = n0 + tx*8 + jj*4;
            float4 bv = *(const float4*)&bias[n];
            float4 o;
            o.x = acc[i][jj*4+0] + bv.x;
            o.y = acc[i][jj*4+1] + bv.y;
            o.z = acc[i][jj*4+2] + bv.z;
            o.w = acc[i][jj*4+3] + bv.w;
            *(float4*)&C[(size_t)m * N + n] = o;
        }
    }
}

// ---------------------------------------------------------------------------
// qtab[b,h,q,t] = sum_d q4[b,q,h,d] * table_k[t,d]   (unchanged R0)
// ---------------------------------------------------------------------------
__global__ __launch_bounds__(256) void qtab_kernel(const float* __restrict__ q4,
                                                   const float* __restrict__ table_k,
                                                   float* __restrict__ qtab) {
    __shared__ float qs[64][68];
    __shared__ float tk[TAB][68];
    const int tid = threadIdx.x;
    const int q0 = blockIdx.x * 64;
    const int h  = blockIdx.y;
    const int b  = blockIdx.z;
    {
        int f = tid;
#pragma unroll
        for (int j = 0; j < 4; ++j, f += 256) {
            int r  = f >> 4;
            int dd = (f & 15) << 2;
            *(float4*)&qs[r][dd] =
                *(const float4*)&q4[((size_t)(b*SEQ + q0 + r)) * HID + h*HD + dd];
        }
    }
    for (int f = tid; f < TAB*16; f += 256) {
        int t  = f >> 4;
        int dd = (f & 15) << 2;
        *(float4*)&tk[t][dd] = *(const float4*)&table_k[t*HD + dd];
    }
    __syncthreads();
    const int tq = tid >> 2;
    const int tg = tid & 3;
    float* outrow = qtab + ((size_t)(b*HEADS + h) * SEQ + q0 + tq) * TAB;
    for (int t = tg; t < TAB; t += 4) {
        float s = 0.f;
#pragma unroll
        for (int d = 0; d < HD; d += 4) {
            float4 qa = *(const float4*)&qs[tq][d];
            float4 ta = *(const float4*)&tk[t][d];
            s = fmaf(qa.x, ta.x, s); s = fmaf(qa.y, ta.y, s);
            s = fmaf(qa.z, ta.z, s); s = fmaf(qa.w, ta.w, s);
        }
        outrow[t] = s;
    }
}

// ---------------------------------------------------------------------------
// helpers: bf16 pack/unpack (bit-exact read path; RNE-ish write path)
// ---------------------------------------------------------------------------
__device__ __forceinline__ ushort f2b(float x) {
    uint b = __float_as_uint(x);
    uint r = (b + 0x7fffu + ((b >> 16) & 1u)) >> 16;
    return (ushort)r;
}
__device__ __forceinline__ uint pk(float lo, float hi) {
    return (uint)f2b(lo) | ((uint)f2b(hi) << 16);
}
__device__ __forceinline__ void unpack8(uint4 u, float* f) {
    f[0] = __uint_as_float(u.x << 16); f[1] = __uint_as_float(u.x & 0xffff0000u);
    f[2] = __uint_as_float(u.y << 16); f[3] = __uint_as_float(u.y & 0xffff0000u);
    f[4] = __uint_as_float(u.z << 16); f[5] = __uint_as_float(u.z & 0xffff0000u);
    f[6] = __uint_as_float(u.w << 16); f[7] = __uint_as_float(u.w & 0xffff0000u);
}

// ---------------------------------------------------------------------------
// Fused attention v2: one block = (b, h, 16 q-rows), 512 threads, ~115 KiB LDS.
//  - kT: K transposed bf16 [d=64][k=512]  -> conflict-free stride-16B QK reads
//  - vS: V bf16 [k=512][d=64], 16B-blocks XOR-swizzled by (k&7)
//  - S : fp32 scores/probs [16][524] (stride chosen for PV-read bank spread)
//  - w2 (bins x table_v) folded into the PV accumulator
// ---------------------------------------------------------------------------
__global__ __launch_bounds__(512) void attn_kernel(const float* __restrict__ qb,
                                                   const float* __restrict__ kb,
                                                   const float* __restrict__ vb,
                                                   const float* __restrict__ qt,
                                                   const int* __restrict__ fmat,
                                                   const float* __restrict__ table_v,
                                                   float* __restrict__ x) {
    __shared__ float  S[16][524];        // 33,536 B
    __shared__ ushort KV[64 * 512];      // 65,536 B  (kT phase A / vS phase C)
    __shared__ float  qT[64][24];        //  6,144 B  (q transposed [d][q])
    __shared__ float  qtb[16][132];      //  8,448 B  (qtab rows, then bins)
    __shared__ float  w1acc[16][68];     //  4,352 B

    const int tid = threadIdx.x;
    // XCD-aware swizzle: 4096 blocks, 8 XCDs -> contiguous 512-chunk per XCD
    const int wg  = blockIdx.x;
    const int swz = (wg & 7) * 512 + (wg >> 3);
    const int qblk = swz & 31;
    const int h    = (swz >> 5) & 15;
    const int b    = swz >> 9;
    const int q0   = qblk * 16;
    const int rowbase = b * SEQ + q0;

    // ---- stage: qtb (qtab rows), qT (q transposed), kT (K transposed bf16) --
    {
        const float* src = qt + ((size_t)(b*HEADS + h) * SEQ + q0) * TAB;
        int r = tid >> 5;                 // 16 rows x 32 threads
        for (int j = tid & 31; j < TAB; j += 32)
            qtb[r][j] = src[r * TAB + j];
    }
    if (tid < 256) {
        int r  = tid >> 4;
        int d0 = (tid & 15) << 2;
        float4 v = *(const float4*)&qb[((size_t)(rowbase + r)) * HID + h*HD + d0];
        qT[d0+0][r] = v.x; qT[d0+1][r] = v.y; qT[d0+2][r] = v.z; qT[d0+3][r] = v.w;
    }
    {
        const int r = tid;                // one K row per thread
        const float* krow = kb + ((size_t)(b*SEQ + r)) * HID + h*HD;
#pragma unroll
        for (int j = 0; j < 16; ++j) {
            float4 v = *(const float4*)&krow[j*4];
            KV[(j*4+0)*512 + r] = f2b(v.x);
            KV[(j*4+1)*512 + r] = f2b(v.y);
            KV[(j*4+2)*512 + r] = f2b(v.z);
            KV[(j*4+3)*512 + r] = f2b(v.w);
        }
    }
    __syncthreads();

    // ---- Phase A: S[q][k] = (q.k + qtab[q][fm]) / 8 ------------------------
    {
        const int qg = tid >> 6;          // wave id: q rows qg*2, qg*2+1
        const int kg = tid & 63;          // k block: kg*8 .. kg*8+7
        float acc0[8], acc1[8];
#pragma unroll
        for (int j = 0; j < 8; ++j) { acc0[j] = 0.f; acc1[j] = 0.f; }
#pragma unroll 4
        for (int d = 0; d < HD; d += 2) {
            float2 qv0 = *(const float2*)&qT[d  ][qg*2];
            float2 qv1 = *(const float2*)&qT[d+1][qg*2];
            uint4 k0 = *(const uint4*)&KV[(d  )*512 + kg*8];
            uint4 k1 = *(const uint4*)&KV[(d+1)*512 + kg*8];
            float f0[8], f1[8];
            unpack8(k0, f0); unpack8(k1, f1);
#pragma unroll
            for (int j = 0; j < 8; ++j) {
                acc0[j] = fmaf(qv0.x, f0[j], acc0[j]);
                acc0[j] = fmaf(qv1.x, f1[j], acc0[j]);
                acc1[j] = fmaf(qv0.y, f0[j], acc1[j]);
                acc1[j] = fmaf(qv1.y, f1[j], acc1[j]);
            }
        }
        // add relative-position term and write scores
#pragma unroll
        for (int rr = 0; rr < 2; ++rr) {
            const int qi = qg*2 + rr;
            const float* accp = rr ? acc1 : acc0;
            const int* fmrow = fmat + ((size_t)(rowbase + qi)) * SEQ + kg*8;
            int4 fm0 = *(const int4*)&fmrow[0];
            int4 fm1 = *(const int4*)&fmrow[4];
            float sc[8];
            sc[0] = (accp[0] + qtb[qi][fm0.x]) * 0.125f;
            sc[1] = (accp[1] + qtb[qi][fm0.y]) * 0.125f;
            sc[2] = (accp[2] + qtb[qi][fm0.z]) * 0.125f;
            sc[3] = (accp[3] + qtb[qi][fm0.w]) * 0.125f;
            sc[4] = (accp[4] + qtb[qi][fm1.x]) * 0.125f;
            sc[5] = (accp[5] + qtb[qi][fm1.y]) * 0.125f;
            sc[6] = (accp[6] + qtb[qi][fm1.z]) * 0.125f;
            sc[7] = (accp[7] + qtb[qi][fm1.w]) * 0.125f;
            *(float4*)&S[qi][kg*8]     = make_float4(sc[0], sc[1], sc[2], sc[3]);
            *(float4*)&S[qi][kg*8 + 4] = make_float4(sc[4], sc[5], sc[6], sc[7]);
        }
    }
    __syncthreads();

    // ---- softmax (per row) + zero qtb/w1acc --------------------------------
    {
        // zero bins and the w1 accumulator
        float* qtbf = &qtb[0][0];
        for (int i = tid; i < 16*132; i += 512) qtbf[i] = 0.f;
        float* w1f = &w1acc[0][0];
        for (int i = tid; i < 16*68; i += 512) w1f[i] = 0.f;

        const int wave = tid >> 6;
        const int lane = tid & 63;
#pragma unroll
        for (int rr = 0; rr < 2; ++rr) {
            const int r = wave*2 + rr;
            float vals[8];
            float vmax = -1e30f;
#pragma unroll
            for (int j = 0; j < 8; ++j) {
                vals[j] = S[r][lane + j*64];
                vmax = fmaxf(vmax, vals[j]);
            }
#pragma unroll
            for (int off = 32; off >= 1; off >>= 1)
                vmax = fmaxf(vmax, __shfl_xor(vmax, off));
            float vsum = 0.f;
#pragma unroll
            for (int j = 0; j < 8; ++j) {
                vals[j] = __expf(vals[j] - vmax);
                vsum += vals[j];
            }
#pragma unroll
            for (int off = 32; off >= 1; off >>= 1)
                vsum += __shfl_xor(vsum, off);
            float inv = 1.f / vsum;
#pragma unroll
            for (int j = 0; j < 8; ++j)
                S[r][lane + j*64] = vals[j] * inv;
        }
    }
    __syncthreads();

    // ---- bins (atomic histogram of attn mass) + stage V (bf16, swizzled) ---
    {
        const int bq = tid & 15;
        const int ks = tid >> 4;          // 32 slices of 16 k
        const int* fmrow = fmat + ((size_t)(rowbase + bq)) * SEQ + ks*16;
#pragma unroll
        for (int jj = 0; jj < 4; ++jj) {
            int4 fm = *(const int4*)&fmrow[jj*4];
            int k = ks*16 + jj*4;
            atomicAdd(&qtb[bq][fm.x], S[bq][k+0]);
            atomicAdd(&qtb[bq][fm.y], S[bq][k+1]);
            atomicAdd(&qtb[bq][fm.z], S[bq][k+2]);
            atomicAdd(&qtb[bq][fm.w], S[bq][k+3]);
        }
    }
    {
        const int r = tid;                // one V row per thread
        const float* vrow = vb + ((size_t)(b*SEQ + r)) * HID + h*HD;
        const int sw = (r & 7);
#pragma unroll
        for (int j = 0; j < 8; ++j) {
            float4 a = *(const float4*)&vrow[j*8];
            float4 c = *(const float4*)&vrow[j*8 + 4];
            uint4 u;
            u.x = pk(a.x, a.y); u.y = pk(a.z, a.w);
            u.z = pk(c.x, c.y); u.w = pk(c.z, c.w);
            *(uint4*)&KV[r*64 + ((j ^ sw) << 3)] = u;
        }
    }
    __syncthreads();

    // ---- Phase C: w1 + w2 into per-thread partials, LDS-atomic reduce ------
    {
        const int dg = tid & 7;           // d block: dg*8
        const int qg = (tid >> 3) & 3;    // q rows: qg + 4i
        const int ks = tid >> 5;          // 16 slices of 32 k
        float acc2[4][8];
#pragma unroll
        for (int i = 0; i < 4; ++i)
#pragma unroll
            for (int c = 0; c < 8; ++c) acc2[i][c] = 0.f;

        const int kb0 = ks * 32;
        for (int kk = kb0; kk < kb0 + 32; kk += 4) {
            float4 p[4];
#pragma unroll
            for (int i = 0; i < 4; ++i)
                p[i] = *(const float4*)&S[qg + 4*i][kk];
            float vv[4][8];
#pragma unroll
            for (int j = 0; j < 4; ++j) {
                uint4 u = *(const uint4*)&KV[(kk+j)*64 + ((dg ^ ((kk+j) & 7)) << 3)];
                unpack8(u, vv[j]);
            }
#pragma unroll
            for (int i = 0; i < 4; ++i) {
                float pj[4] = {p[i].x, p[i].y, p[i].z, p[i].w};
#pragma unroll
                for (int j = 0; j < 4; ++j)
#pragma unroll
                    for (int c = 0; c < 8; ++c)
                        acc2[i][c] = fmaf(pj[j], vv[j][c], acc2[i][c]);
            }
        }
        // w2: bins x table_v folded in (t-slices across ks)
#pragma unroll
        for (int j = 0; j < 9; ++j) {
            int t = ks + 16*j;
            if (t < TAB) {
                float4 t0 = *(const float4*)&table_v[t*HD + dg*8];
                float4 t1 = *(const float4*)&table_v[t*HD + dg*8 + 4];
                float tv[8] = {t0.x, t0.y, t0.z, t0.w, t1.x, t1.y, t1.z, t1.w};
#pragma unroll
                for (int i = 0; i < 4; ++i) {
                    float sv = qtb[qg + 4*i][t];
#pragma unroll
                    for (int c = 0; c < 8; ++c)
                        acc2[i][c] = fmaf(sv, tv[c], acc2[i][c]);
                }
            }
        }
#pragma unroll
        for (int i = 0; i < 4; ++i)
#pragma unroll
            for (int c = 0; c < 8; ++c)
                atomicAdd(&w1acc[qg + 4*i][dg*8 + c], acc2[i][c]);
    }
    __syncthreads();

    // ---- epilogue: write x ---------------------------------------------------
    if (tid < 256) {
        const int q  = tid >> 4;
        const int d0 = (tid & 15) << 2;
        float4 o = *(const float4*)&w1acc[q][d0];
        *(float4*)&x[((size_t)(rowbase + q)) * HID + h*HD + d0] = o;
    }
}

// ---------------------------------------------------------------------------
extern "C" void kernel_launch(void* const* d_in, const int* in_sizes, int n_in,
                              void* d_out, int out_size, void* d_ws, size_t ws_size,
                              hipStream_t stream) {
    const float* query = (const float*)d_in[0];
    const float* key   = (const float*)d_in[1];
    const float* value = (const float*)d_in[2];
    const int*   fmat  = (const int*)d_in[3];
    const float* Wq = (const float*)d_in[4];
    const float* bq = (const float*)d_in[5];
    const float* Wk = (const float*)d_in[6];
    const float* bk = (const float*)d_in[7];
    const float* Wv = (const float*)d_in[8];
    const float* bv = (const float*)d_in[9];
    const float* Wo = (const float*)d_in[10];
    const float* bo = (const float*)d_in[11];
    const float* table_k = (const float*)d_in[12];
    const float* table_v = (const float*)d_in[13];

    const size_t nBLD = (size_t)BATCH * SEQ * HID;
    float* ws = (float*)d_ws;
    float* qbuf = ws;
    float* kbuf = qbuf + nBLD;
    float* vbuf = kbuf + nBLD;
    float* qtab = vbuf + nBLD;
    float* xbuf = qtab + (size_t)BATCH * HEADS * SEQ * TAB;

    const int M = BATCH * SEQ;  // 4096
    dim3 ggrid(HID / 128, M / 128);

    gemm_nt_bias<<<ggrid, 256, 0, stream>>>(query, Wq, bq, qbuf, M, HID, HID);
    gemm_nt_bias<<<ggrid, 256, 0, stream>>>(key,   Wk, bk, kbuf, M, HID, HID);
    gemm_nt_bias<<<ggrid, 256, 0, stream>>>(value, Wv, bv, vbuf, M, HID, HID);

    qtab_kernel<<<dim3(SEQ/64, HEADS, BATCH), 256, 0, stream>>>(qbuf, table_k, qtab);

    attn_kernel<<<dim3(BATCH * HEADS * (SEQ/16)), 512, 0, stream>>>(
        qbuf, kbuf, vbuf, qtab, fmat, table_v, xbuf);

    gemm_nt_bias<<<ggrid, 256, 0, stream>>>(xbuf, Wo, bo, (float*)d_out, M, HID, HID);
}

// Round 3
// 746.918 us; speedup vs baseline: 1.7467x; 1.7467x over previous
//
#include <hip/hip_runtime.h>

#define HID 1024
#define HEADS 16
#define HD 64
#define TAB 129
#define BATCH 8
#define SEQ 512

typedef unsigned int uint;
typedef unsigned short ushort;
typedef __attribute__((ext_vector_type(4))) float f32x4;
typedef __attribute__((ext_vector_type(8))) __bf16 bf16x8;

// ---------------------------------------------------------------------------
// bf16 helpers (RNE pack, bit-exact unpack)
// ---------------------------------------------------------------------------
__device__ __forceinline__ ushort f2b(float x) {
    uint b = __float_as_uint(x);
    uint r = (b + 0x7fffu + ((b >> 16) & 1u)) >> 16;
    return (ushort)r;
}
__device__ __forceinline__ uint pk(float lo, float hi) {
    return (uint)f2b(lo) | ((uint)f2b(hi) << 16);
}
__device__ __forceinline__ float b2f(ushort u) {
    return __uint_as_float(((uint)u) << 16);
}
union U16x8 { uint u[4]; bf16x8 v; };
__device__ __forceinline__ bf16x8 pack8(float a0, float a1, float a2, float a3,
                                        float a4, float a5, float a6, float a7) {
    U16x8 r;
    r.u[0] = pk(a0, a1); r.u[1] = pk(a2, a3);
    r.u[2] = pk(a4, a5); r.u[3] = pk(a6, a7);
    return r.v;
}

// ---------------------------------------------------------------------------
// C[M,N] = A[M,K] @ W[N,K]^T + bias[N]   (fp32 vector GEMM, unchanged R0)
// ---------------------------------------------------------------------------
__global__ __launch_bounds__(256) void gemm_nt_bias(const float* __restrict__ A,
                                                    const float* __restrict__ W,
                                                    const float* __restrict__ bias,
                                                    float* __restrict__ C,
                                                    int M, int N, int K) {
    __shared__ float As[16][132];
    __shared__ float Ws[16][132];
    const int tid = threadIdx.x;
    const int m0 = blockIdx.y * 128;
    const int n0 = blockIdx.x * 128;
    const int tx = tid & 15;
    const int ty = tid >> 4;
    const int lr = tid >> 2;
    const int lk = (tid & 3) << 2;

    float acc[8][8];
#pragma unroll
    for (int i = 0; i < 8; ++i)
#pragma unroll
        for (int j = 0; j < 8; ++j) acc[i][j] = 0.f;

    const float* Arow0 = A + (size_t)(m0 + lr) * K + lk;
    const float* Arow1 = A + (size_t)(m0 + lr + 64) * K + lk;
    const float* Wrow0 = W + (size_t)(n0 + lr) * K + lk;
    const float* Wrow1 = W + (size_t)(n0 + lr + 64) * K + lk;

    for (int k0 = 0; k0 < K; k0 += 16) {
        float4 a0 = *(const float4*)(Arow0 + k0);
        float4 a1 = *(const float4*)(Arow1 + k0);
        float4 w0 = *(const float4*)(Wrow0 + k0);
        float4 w1 = *(const float4*)(Wrow1 + k0);
        __syncthreads();
        As[lk+0][lr]    = a0.x; As[lk+1][lr]    = a0.y; As[lk+2][lr]    = a0.z; As[lk+3][lr]    = a0.w;
        As[lk+0][lr+64] = a1.x; As[lk+1][lr+64] = a1.y; As[lk+2][lr+64] = a1.z; As[lk+3][lr+64] = a1.w;
        Ws[lk+0][lr]    = w0.x; Ws[lk+1][lr]    = w0.y; Ws[lk+2][lr]    = w0.z; Ws[lk+3][lr]    = w0.w;
        Ws[lk+0][lr+64] = w1.x; Ws[lk+1][lr+64] = w1.y; Ws[lk+2][lr+64] = w1.z; Ws[lk+3][lr+64] = w1.w;
        __syncthreads();
#pragma unroll
        for (int kk = 0; kk < 16; ++kk) {
            float4 av0 = *(const float4*)&As[kk][ty*8];
            float4 av1 = *(const float4*)&As[kk][ty*8+4];
            float4 wv0 = *(const float4*)&Ws[kk][tx*8];
            float4 wv1 = *(const float4*)&Ws[kk][tx*8+4];
            float am[8] = {av0.x, av0.y, av0.z, av0.w, av1.x, av1.y, av1.z, av1.w};
            float wn[8] = {wv0.x, wv0.y, wv0.z, wv0.w, wv1.x, wv1.y, wv1.z, wv1.w};
#pragma unroll
            for (int i = 0; i < 8; ++i)
#pragma unroll
                for (int j = 0; j < 8; ++j)
                    acc[i][j] = fmaf(am[i], wn[j], acc[i][j]);
        }
    }
#pragma unroll
    for (int i = 0; i < 8; ++i) {
        int m = m0 + ty*8 + i;
#pragma unroll
        for (int jj = 0; jj < 2; ++jj) {
            int n = n0 + tx*8 + jj*4;
            float4 bv = *(const float4*)&bias[n];
            float4 o;
            o.x = acc[i][jj*4+0] + bv.x;
            o.y = acc[i][jj*4+1] + bv.y;
            o.z = acc[i][jj*4+2] + bv.z;
            o.w = acc[i][jj*4+3] + bv.w;
            *(float4*)&C[(size_t)m * N + n] = o;
        }
    }
}

// ---------------------------------------------------------------------------
// qtab[b,h,q,t] = sum_d q4[b,q,h,d] * table_k[t,d]   (unchanged R0)
// ---------------------------------------------------------------------------
__global__ __launch_bounds__(256) void qtab_kernel(const float* __restrict__ q4,
                                                   const float* __restrict__ table_k,
                                                   float* __restrict__ qtab) {
    __shared__ float qs[64][68];
    __shared__ float tk[TAB][68];
    const int tid = threadIdx.x;
    const int q0 = blockIdx.x * 64;
    const int h  = blockIdx.y;
    const int b  = blockIdx.z;
    {
        int f = tid;
#pragma unroll
        for (int j = 0; j < 4; ++j, f += 256) {
            int r  = f >> 4;
            int dd = (f & 15) << 2;
            *(float4*)&qs[r][dd] =
                *(const float4*)&q4[((size_t)(b*SEQ + q0 + r)) * HID + h*HD + dd];
        }
    }
    for (int f = tid; f < TAB*16; f += 256) {
        int t  = f >> 4;
        int dd = (f & 15) << 2;
        *(float4*)&tk[t][dd] = *(const float4*)&table_k[t*HD + dd];
    }
    __syncthreads();
    const int tq = tid >> 2;
    const int tg = tid & 3;
    float* outrow = qtab + ((size_t)(b*HEADS + h) * SEQ + q0 + tq) * TAB;
    for (int t = tg; t < TAB; t += 4) {
        float s = 0.f;
#pragma unroll
        for (int d = 0; d < HD; d += 4) {
            float4 qa = *(const float4*)&qs[tq][d];
            float4 ta = *(const float4*)&tk[t][d];
            s = fmaf(qa.x, ta.x, s); s = fmaf(qa.y, ta.y, s);
            s = fmaf(qa.z, ta.z, s); s = fmaf(qa.w, ta.w, s);
        }
        outrow[t] = s;
    }
}

// ---------------------------------------------------------------------------
// Fused attention v3 (MFMA): one block = (b, h, 64 q-rows), 256 thr, 78.6 KB LDS.
// Streaming no-max softmax: s=(q·k + qtab[fm])/8 is bounded (|s|<~3), so
// p=exp(s) accumulated unnormalized; divide by row-sum at the end.
//   QK^T as ST = Ktile·Q^T  -> lane owns one q-row's scores (gather/exp/bins lane-local)
//   PV  via per-wave P bounce tile;  w2 = bins·table_v as 4 more MFMAs.
// Only the (verified) C/D layout matters; A/B k-grouping cancels since both
// operands of every MFMA are loaded with the same spatial map.
// ---------------------------------------------------------------------------
__global__ __launch_bounds__(256) void attn_mfma(const float* __restrict__ qp,
                                                 const float* __restrict__ kp,
                                                 const float* __restrict__ vp,
                                                 const float* __restrict__ qt,
                                                 const int* __restrict__ fmat,
                                                 const float* __restrict__ table_v,
                                                 float* __restrict__ x) {
    __shared__ ushort qtb[64 * 132];      // 16,896 B  qtab rows, bf16
    __shared__ float  sbin[64 * 132];     // 33,792 B  attention-mass bins (fp32)
    __shared__ ushort KVT[9216];          // 18,432 B  KT[64][72] + VT[64][72]; tvT overlay [64][136]
    __shared__ ushort PL[4][16 * 72];     //  9,216 B  per-wave P tile [q][k]
    __shared__ float  rowinv[4][16];      //    256 B

    ushort* KT = KVT;
    ushort* VT = KVT + 64 * 72;

    const int tid = threadIdx.x;
    const int wq  = tid >> 6;             // wave 0..3 -> q rows wq*16..+15
    const int l   = tid & 63;
    const int lr  = l & 15;
    const int lg  = l >> 4;

    // XCD-bijective swizzle: 1024 blocks, chunks of 128 per XCD ->
    // all 16 heads of a (b, qblk) group land on one XCD (fm tile L2-hot).
    const int wg   = blockIdx.x;
    const int work = (wg & 7) * 128 + (wg >> 3);
    const int h    = work & 15;
    const int qblk = (work >> 4) & 7;
    const int b    = work >> 7;
    const int q0   = qblk * 64;

    // ---- stage qtab rows (bf16) + zero bins ----
    for (int i = tid; i < 64 * TAB; i += 256) {
        int r = i / TAB, t = i - r * TAB;
        qtb[r * 132 + t] = f2b(qt[((size_t)(b * HEADS + h) * SEQ + q0 + r) * TAB + t]);
    }
    for (int i = tid; i < 64 * 132; i += 256) sbin[i] = 0.f;

    // ---- Q fragments (per wave; rows wq*16+lr), used as MFMA B-operand ----
    bf16x8 qfrag[2];
    {
        const float* qrow = qp + ((size_t)(b * SEQ + q0 + wq * 16 + lr)) * HID + h * HD;
#pragma unroll
        for (int ks = 0; ks < 2; ++ks) {
            float4 a = *(const float4*)(qrow + ks * 32 + lg * 8);
            float4 c = *(const float4*)(qrow + ks * 32 + lg * 8 + 4);
            qfrag[ks] = pack8(a.x, a.y, a.z, a.w, c.x, c.y, c.z, c.w);
        }
    }

    f32x4 acc_o[4];
#pragma unroll
    for (int nt = 0; nt < 4; ++nt) acc_o[nt] = (f32x4){0.f, 0.f, 0.f, 0.f};
    float lsum = 0.f;

    const int  qrow_l = wq * 16 + lr;     // this lane's q row (ST col)
    const int* fmrow  = fmat + ((size_t)(b * SEQ) + q0 + qrow_l) * SEQ;

    __syncthreads();

    for (int kt = 0; kt < 8; ++kt) {
        const int k0 = kt * 64;
        // ---- stage K tile (row-major bf16) + V tile (transposed bf16) ----
        {
            const int sk = tid >> 2;
            const int sd = (tid & 3) * 16;
            const float* krow = kp + ((size_t)(b * SEQ + k0 + sk)) * HID + h * HD + sd;
            const float* vrow = vp + ((size_t)(b * SEQ + k0 + sk)) * HID + h * HD + sd;
            float4 ka  = *(const float4*)(krow);
            float4 kb4 = *(const float4*)(krow + 4);
            float4 kc  = *(const float4*)(krow + 8);
            float4 kd  = *(const float4*)(krow + 12);
            uint4 u0, u1;
            u0.x = pk(ka.x, ka.y);   u0.y = pk(ka.z, ka.w);
            u0.z = pk(kb4.x, kb4.y); u0.w = pk(kb4.z, kb4.w);
            u1.x = pk(kc.x, kc.y);   u1.y = pk(kc.z, kc.w);
            u1.z = pk(kd.x, kd.y);   u1.w = pk(kd.z, kd.w);
            *(uint4*)&KT[sk * 72 + sd]     = u0;
            *(uint4*)&KT[sk * 72 + sd + 8] = u1;
            float4 va  = *(const float4*)(vrow);
            float4 vb4 = *(const float4*)(vrow + 4);
            float4 vc  = *(const float4*)(vrow + 8);
            float4 vd  = *(const float4*)(vrow + 12);
            float vv[16] = {va.x, va.y, va.z, va.w, vb4.x, vb4.y, vb4.z, vb4.w,
                            vc.x, vc.y, vc.z, vc.w, vd.x, vd.y, vd.z, vd.w};
#pragma unroll
            for (int i2 = 0; i2 < 16; ++i2)
                VT[(sd + i2) * 72 + sk] = f2b(vv[i2]);
        }
        __syncthreads();

        // ---- ST = Ktile·Q^T -> scores -> exp -> bins/lsum -> P tile ----
#pragma unroll
        for (int mt = 0; mt < 4; ++mt) {
            bf16x8 ka0 = *(const bf16x8*)&KT[(mt * 16 + lr) * 72 + lg * 8];
            bf16x8 ka1 = *(const bf16x8*)&KT[(mt * 16 + lr) * 72 + 32 + lg * 8];
            f32x4 st = (f32x4){0.f, 0.f, 0.f, 0.f};
            st = __builtin_amdgcn_mfma_f32_16x16x32_bf16(ka0, qfrag[0], st, 0, 0, 0);
            st = __builtin_amdgcn_mfma_f32_16x16x32_bf16(ka1, qfrag[1], st, 0, 0, 0);
            // C layout: reg r -> k = k0 + mt*16 + lg*4 + r, col lr -> q row
            const int4 fm4 = *(const int4*)&fmrow[k0 + mt * 16 + lg * 4];
            float pr0 = __expf((st[0] + b2f(qtb[qrow_l * 132 + fm4.x])) * 0.125f);
            float pr1 = __expf((st[1] + b2f(qtb[qrow_l * 132 + fm4.y])) * 0.125f);
            float pr2 = __expf((st[2] + b2f(qtb[qrow_l * 132 + fm4.z])) * 0.125f);
            float pr3 = __expf((st[3] + b2f(qtb[qrow_l * 132 + fm4.w])) * 0.125f);
            lsum += pr0 + pr1 + pr2 + pr3;
            atomicAdd(&sbin[qrow_l * 132 + fm4.x], pr0);
            atomicAdd(&sbin[qrow_l * 132 + fm4.y], pr1);
            atomicAdd(&sbin[qrow_l * 132 + fm4.z], pr2);
            atomicAdd(&sbin[qrow_l * 132 + fm4.w], pr3);
            uint2 pu;
            pu.x = pk(pr0, pr1); pu.y = pk(pr2, pr3);
            *(uint2*)&PL[wq][lr * 72 + mt * 16 + lg * 4] = pu;  // true-k position
        }
        // ---- PV: O += P · Vtile ----
        {
            bf16x8 pa0 = *(const bf16x8*)&PL[wq][lr * 72 + lg * 8];
            bf16x8 pa1 = *(const bf16x8*)&PL[wq][lr * 72 + 32 + lg * 8];
#pragma unroll
            for (int nt = 0; nt < 4; ++nt) {
                bf16x8 vb0 = *(const bf16x8*)&VT[(nt * 16 + lr) * 72 + lg * 8];
                bf16x8 vb1 = *(const bf16x8*)&VT[(nt * 16 + lr) * 72 + 32 + lg * 8];
                acc_o[nt] = __builtin_amdgcn_mfma_f32_16x16x32_bf16(pa0, vb0, acc_o[nt], 0, 0, 0);
                acc_o[nt] = __builtin_amdgcn_mfma_f32_16x16x32_bf16(pa1, vb1, acc_o[nt], 0, 0, 0);
            }
        }
        __syncthreads();
    }

    // ---- row sums -> 1/l ; normalize w1 part ----
    lsum += __shfl_xor(lsum, 16);
    lsum += __shfl_xor(lsum, 32);
    const float invl = 1.f / lsum;        // valid for q = wq*16+lr on every lane
    if (lg == 0) rowinv[wq][lr] = invl;

    float iv[4];
#pragma unroll
    for (int r = 0; r < 4; ++r) iv[r] = rowinv[wq][lg * 4 + r];
#pragma unroll
    for (int nt = 0; nt < 4; ++nt)
#pragma unroll
        for (int r = 0; r < 4; ++r) acc_o[nt][r] *= iv[r];

    // ---- stage tvT overlay (table_v transposed, bf16, t=0..127) ----
    {
        const int tt = tid >> 1;          // 0..127
        const int d0 = (tid & 1) * 32;
        const float* tvrow = table_v + (size_t)tt * HD + d0;
#pragma unroll
        for (int i2 = 0; i2 < 32; i2 += 4) {
            float4 a = *(const float4*)(tvrow + i2);
            KVT[(d0 + i2 + 0) * 136 + tt] = f2b(a.x);
            KVT[(d0 + i2 + 1) * 136 + tt] = f2b(a.y);
            KVT[(d0 + i2 + 2) * 136 + tt] = f2b(a.z);
            KVT[(d0 + i2 + 3) * 136 + tt] = f2b(a.w);
        }
    }
    __syncthreads();

    // ---- w2: O += (bins/l) · table_v  (4 k-steps of MFMA + t=128 tail) ----
#pragma unroll
    for (int ks = 0; ks < 4; ++ks) {
        const float* sp = &sbin[qrow_l * 132 + ks * 32 + lg * 8];
        f32x4 s0 = *(const f32x4*)sp;
        f32x4 s1 = *(const f32x4*)(sp + 4);
        bf16x8 af = pack8(s0[0]*invl, s0[1]*invl, s0[2]*invl, s0[3]*invl,
                          s1[0]*invl, s1[1]*invl, s1[2]*invl, s1[3]*invl);
#pragma unroll
        for (int nt = 0; nt < 4; ++nt) {
            bf16x8 bf_ = *(const bf16x8*)&KVT[(nt * 16 + lr) * 136 + ks * 32 + lg * 8];
            acc_o[nt] = __builtin_amdgcn_mfma_f32_16x16x32_bf16(af, bf_, acc_o[nt], 0, 0, 0);
        }
    }
    {
        float nb[4];
#pragma unroll
        for (int r = 0; r < 4; ++r)
            nb[r] = sbin[(wq * 16 + lg * 4 + r) * 132 + 128] * iv[r];
#pragma unroll
        for (int nt = 0; nt < 4; ++nt) {
            float tv = table_v[(size_t)128 * HD + nt * 16 + lr];
#pragma unroll
            for (int r = 0; r < 4; ++r)
                acc_o[nt][r] = fmaf(nb[r], tv, acc_o[nt][r]);
        }
    }

    // ---- write x: C layout row = lg*4+r, col = nt*16+lr ----
    {
        float* orow = x + ((size_t)(b * SEQ + q0 + wq * 16 + lg * 4)) * HID + h * HD;
#pragma unroll
        for (int r = 0; r < 4; ++r)
#pragma unroll
            for (int nt = 0; nt < 4; ++nt)
                orow[(size_t)r * HID + nt * 16 + lr] = acc_o[nt][r];
    }
}

// ---------------------------------------------------------------------------
extern "C" void kernel_launch(void* const* d_in, const int* in_sizes, int n_in,
                              void* d_out, int out_size, void* d_ws, size_t ws_size,
                              hipStream_t stream) {
    const float* query = (const float*)d_in[0];
    const float* key   = (const float*)d_in[1];
    const float* value = (const float*)d_in[2];
    const int*   fmat  = (const int*)d_in[3];
    const float* Wq = (const float*)d_in[4];
    const float* bq = (const float*)d_in[5];
    const float* Wk = (const float*)d_in[6];
    const float* bk = (const float*)d_in[7];
    const float* Wv = (const float*)d_in[8];
    const float* bv = (const float*)d_in[9];
    const float* Wo = (const float*)d_in[10];
    const float* bo = (const float*)d_in[11];
    const float* table_k = (const float*)d_in[12];
    const float* table_v = (const float*)d_in[13];

    const size_t nBLD = (size_t)BATCH * SEQ * HID;
    float* ws = (float*)d_ws;
    float* qbuf = ws;
    float* kbuf = qbuf + nBLD;
    float* vbuf = kbuf + nBLD;
    float* qtab = vbuf + nBLD;
    float* xbuf = qtab + (size_t)BATCH * HEADS * SEQ * TAB;

    const int M = BATCH * SEQ;  // 4096
    dim3 ggrid(HID / 128, M / 128);

    gemm_nt_bias<<<ggrid, 256, 0, stream>>>(query, Wq, bq, qbuf, M, HID, HID);
    gemm_nt_bias<<<ggrid, 256, 0, stream>>>(key,   Wk, bk, kbuf, M, HID, HID);
    gemm_nt_bias<<<ggrid, 256, 0, stream>>>(value, Wv, bv, vbuf, M, HID, HID);

    qtab_kernel<<<dim3(SEQ/64, HEADS, BATCH), 256, 0, stream>>>(qbuf, table_k, qtab);

    attn_mfma<<<dim3(BATCH * HEADS * (SEQ/64)), 256, 0, stream>>>(
        qbuf, kbuf, vbuf, qtab, fmat, table_v, xbuf);

    gemm_nt_bias<<<ggrid, 256, 0, stream>>>(xbuf, Wo, bo, (float*)d_out, M, HID, HID);
}

// Round 4
// 348.490 us; speedup vs baseline: 3.7438x; 2.1433x over previous
//
#include <hip/hip_runtime.h>

#define HID 1024
#define HEADS 16
#define HD 64
#define TAB 129
#define BATCH 8
#define SEQ 512

typedef unsigned int uint;
typedef unsigned short ushort;
typedef __attribute__((ext_vector_type(4))) float f32x4;
typedef __attribute__((ext_vector_type(8))) __bf16 bf16x8;

// ---------------------------------------------------------------------------
// bf16 helpers
// ---------------------------------------------------------------------------
__device__ __forceinline__ ushort f2b(float x) {
    uint b = __float_as_uint(x);
    uint r = (b + 0x7fffu + ((b >> 16) & 1u)) >> 16;
    return (ushort)r;
}
__device__ __forceinline__ uint pk(float lo, float hi) {
    return (uint)f2b(lo) | ((uint)f2b(hi) << 16);
}
__device__ __forceinline__ float b2f(ushort u) {
    return __uint_as_float(((uint)u) << 16);
}
__device__ __forceinline__ void unpack8(uint4 u, float* f) {
    f[0] = __uint_as_float(u.x << 16); f[1] = __uint_as_float(u.x & 0xffff0000u);
    f[2] = __uint_as_float(u.y << 16); f[3] = __uint_as_float(u.y & 0xffff0000u);
    f[4] = __uint_as_float(u.z << 16); f[5] = __uint_as_float(u.z & 0xffff0000u);
    f[6] = __uint_as_float(u.w << 16); f[7] = __uint_as_float(u.w & 0xffff0000u);
}
union U16x8 { uint u[4]; bf16x8 v; ushort s[8]; };
__device__ __forceinline__ bf16x8 pack8(float a0, float a1, float a2, float a3,
                                        float a4, float a5, float a6, float a7) {
    U16x8 r;
    r.u[0] = pk(a0, a1); r.u[1] = pk(a2, a3);
    r.u[2] = pk(a4, a5); r.u[3] = pk(a6, a7);
    return r.v;
}

#define GL16(gp, lp) __builtin_amdgcn_global_load_lds( \
    (const __attribute__((address_space(1))) void*)(gp), \
    (__attribute__((address_space(3))) void*)(lp), 16, 0, 0)

// ---------------------------------------------------------------------------
// convert fp32 -> bf16: query,key,value (4M elems each), Wq,Wk,Wv,Wo (1M each)
// one block = 2048 elems; 8192 blocks total.
// ---------------------------------------------------------------------------
struct ConvArgs { const float* src[7]; ushort* dst[7]; };

__global__ __launch_bounds__(256) void convert_bf16(ConvArgs ca) {
    int bid = blockIdx.x;
    int ti, lb;
    if (bid < 6144) { ti = bid >> 11; lb = bid & 2047; }
    else { int r = bid - 6144; ti = 3 + (r >> 9); lb = r & 511; }
    const float* s = ca.src[ti] + (size_t)lb * 2048 + (threadIdx.x << 3);
    ushort*      d = ca.dst[ti] + (size_t)lb * 2048 + (threadIdx.x << 3);
    float4 a = *(const float4*)s;
    float4 c = *(const float4*)(s + 4);
    uint4 u;
    u.x = pk(a.x, a.y); u.y = pk(a.z, a.w);
    u.z = pk(c.x, c.y); u.w = pk(c.z, c.w);
    *(uint4*)d = u;
}

// ---------------------------------------------------------------------------
// bf16 MFMA GEMM: C_z = A_z[M,K] @ W_z[N,K]^T + bias_z, z = blockIdx.z.
// 128x128 tile, BK=32, 256 thr (4 waves 2x2), double-buffered LDS via
// global_load_lds (linear dest, inverse-swizzled source, swizzled ds_read).
// Output: fp32 (Cf) or bf16 (Cb), whichever is non-null.
// ---------------------------------------------------------------------------
struct GemmArgs {
    const ushort* A[3];
    const ushort* W[3];
    const float*  bias[3];
    float*        Cf[3];
    ushort*       Cb[3];
};

__global__ __launch_bounds__(256) void gemm_bf16(GemmArgs ga, int M, int N, int K) {
    __shared__ ushort As[2][128 * 32];
    __shared__ ushort Bs[2][128 * 32];
    const int z = blockIdx.z;
    const ushort* A = ga.A[z];
    const ushort* W = ga.W[z];
    const int tid = threadIdx.x;
    const int m0 = blockIdx.y * 128;
    const int n0 = blockIdx.x * 128;

    const int w  = tid >> 6;
    const int l  = tid & 63;
    const int lr = l & 15;
    const int lg = l >> 4;
    const int wm = w >> 1;
    const int wn = w & 1;

    // staging: thread t -> tile row sr (and sr+64), LDS slot sc; the data for
    // slot (r,c) is global k-group g = c ^ ((r>>1)&3)  (involution)
    const int sr = tid >> 2;
    const int sc = tid & 3;
    const int g  = sc ^ ((sr >> 1) & 3);
    const ushort* Ag0 = A + (size_t)(m0 + sr)      * K + g * 8;
    const ushort* Ag1 = A + (size_t)(m0 + sr + 64) * K + g * 8;
    const ushort* Wg0 = W + (size_t)(n0 + sr)      * K + g * 8;
    const ushort* Wg1 = W + (size_t)(n0 + sr + 64) * K + g * 8;

    f32x4 acc[4][4];
#pragma unroll
    for (int mt = 0; mt < 4; ++mt)
#pragma unroll
        for (int nt = 0; nt < 4; ++nt) acc[mt][nt] = (f32x4){0.f, 0.f, 0.f, 0.f};

#define STAGE(buf, k0) do { \
        GL16(Ag0 + (k0), &As[buf][w * 512]); \
        GL16(Ag1 + (k0), &As[buf][2048 + w * 512]); \
        GL16(Wg0 + (k0), &Bs[buf][w * 512]); \
        GL16(Wg1 + (k0), &Bs[buf][2048 + w * 512]); \
    } while (0)

    const int swz = (lr >> 1) & 3;
#define COMPUTE(buf) do { \
        bf16x8 af[4], bf[4]; \
        _Pragma("unroll") \
        for (int mt = 0; mt < 4; ++mt) \
            af[mt] = *(const bf16x8*)&As[buf][(wm * 64 + mt * 16 + lr) * 32 + (lg ^ swz) * 8]; \
        _Pragma("unroll") \
        for (int nt = 0; nt < 4; ++nt) \
            bf[nt] = *(const bf16x8*)&Bs[buf][(wn * 64 + nt * 16 + lr) * 32 + (lg ^ swz) * 8]; \
        _Pragma("unroll") \
        for (int mt = 0; mt < 4; ++mt) \
            _Pragma("unroll") \
            for (int nt = 0; nt < 4; ++nt) \
                acc[mt][nt] = __builtin_amdgcn_mfma_f32_16x16x32_bf16(af[mt], bf[nt], acc[mt][nt], 0, 0, 0); \
    } while (0)

    STAGE(0, 0);
    __syncthreads();
    const int nk = K / 32;
    for (int t = 0; t < nk - 1; ++t) {
        STAGE((t + 1) & 1, (size_t)(t + 1) * 32);
        COMPUTE(t & 1);
        __syncthreads();
    }
    COMPUTE((nk - 1) & 1);

    // epilogue: C row = lg*4 + r (m), col = lr (n) within each 16x16 tile
    const float* bias = ga.bias[z];
    float bv[4];
#pragma unroll
    for (int nt = 0; nt < 4; ++nt) bv[nt] = bias[n0 + wn * 64 + nt * 16 + lr];
    float*  Cf = ga.Cf[z];
    ushort* Cb = ga.Cb[z];
    if (Cf) {
#pragma unroll
        for (int mt = 0; mt < 4; ++mt)
#pragma unroll
            for (int r4 = 0; r4 < 4; ++r4) {
                size_t m = m0 + wm * 64 + mt * 16 + lg * 4 + r4;
                float* crow = Cf + m * N + n0 + wn * 64 + lr;
#pragma unroll
                for (int nt = 0; nt < 4; ++nt)
                    crow[nt * 16] = acc[mt][nt][r4] + bv[nt];
            }
    } else {
#pragma unroll
        for (int mt = 0; mt < 4; ++mt)
#pragma unroll
            for (int r4 = 0; r4 < 4; ++r4) {
                size_t m = m0 + wm * 64 + mt * 16 + lg * 4 + r4;
                ushort* crow = Cb + m * N + n0 + wn * 64 + lr;
#pragma unroll
                for (int nt = 0; nt < 4; ++nt)
                    crow[nt * 16] = f2b(acc[mt][nt][r4] + bv[nt]);
            }
    }
#undef STAGE
#undef COMPUTE
}

// ---------------------------------------------------------------------------
// qtab[b,h,q,t] = sum_d q4[b,q,h,d] * table_k[t,d]   (bf16 q in, bf16 out)
// ---------------------------------------------------------------------------
__global__ __launch_bounds__(256) void qtab_kernel(const ushort* __restrict__ q4,
                                                   const float* __restrict__ table_k,
                                                   ushort* __restrict__ qtab) {
    __shared__ float qs[64][68];
    __shared__ float tk[TAB][68];
    const int tid = threadIdx.x;
    const int q0 = blockIdx.x * 64;
    const int h  = blockIdx.y;
    const int b  = blockIdx.z;
    for (int f = tid; f < 512; f += 256) {
        int r  = f >> 3;
        int dd = (f & 7) << 3;
        uint4 u = *(const uint4*)&q4[((size_t)(b*SEQ + q0 + r)) * HID + h*HD + dd];
        float f8[8];
        unpack8(u, f8);
#pragma unroll
        for (int j = 0; j < 8; ++j) qs[r][dd + j] = f8[j];
    }
    for (int f = tid; f < TAB*16; f += 256) {
        int t  = f >> 4;
        int dd = (f & 15) << 2;
        *(float4*)&tk[t][dd] = *(const float4*)&table_k[t*HD + dd];
    }
    __syncthreads();
    const int tq = tid >> 2;
    const int tg = tid & 3;
    ushort* outrow = qtab + ((size_t)(b*HEADS + h) * SEQ + q0 + tq) * TAB;
    for (int t = tg; t < TAB; t += 4) {
        float s = 0.f;
#pragma unroll
        for (int d = 0; d < HD; d += 4) {
            float4 qa = *(const float4*)&qs[tq][d];
            float4 ta = *(const float4*)&tk[t][d];
            s = fmaf(qa.x, ta.x, s); s = fmaf(qa.y, ta.y, s);
            s = fmaf(qa.z, ta.z, s); s = fmaf(qa.w, ta.w, s);
        }
        outrow[t] = f2b(s);
    }
}

// ---------------------------------------------------------------------------
// Fused attention (MFMA, R3 structure; bf16 inputs/outputs)
// ---------------------------------------------------------------------------
__global__ __launch_bounds__(256) void attn_mfma(const ushort* __restrict__ qp,
                                                 const ushort* __restrict__ kp,
                                                 const ushort* __restrict__ vp,
                                                 const ushort* __restrict__ qt,
                                                 const int* __restrict__ fmat,
                                                 const float* __restrict__ table_v,
                                                 ushort* __restrict__ x) {
    __shared__ ushort qtb[64 * 132];
    __shared__ float  sbin[64 * 132];
    __shared__ ushort KVT[9216];
    __shared__ ushort PL[4][16 * 72];
    __shared__ float  rowinv[4][16];

    ushort* KT = KVT;
    ushort* VT = KVT + 64 * 72;

    const int tid = threadIdx.x;
    const int wq  = tid >> 6;
    const int l   = tid & 63;
    const int lr  = l & 15;
    const int lg  = l >> 4;

    const int wg   = blockIdx.x;
    const int work = (wg & 7) * 128 + (wg >> 3);
    const int h    = work & 15;
    const int qblk = (work >> 4) & 7;
    const int b    = work >> 7;
    const int q0   = qblk * 64;

    for (int i = tid; i < 64 * TAB; i += 256) {
        int r = i / TAB, t = i - r * TAB;
        qtb[r * 132 + t] = qt[((size_t)(b * HEADS + h) * SEQ + q0 + r) * TAB + t];
    }
    for (int i = tid; i < 64 * 132; i += 256) sbin[i] = 0.f;

    bf16x8 qfrag[2];
    {
        const ushort* qrow = qp + ((size_t)(b * SEQ + q0 + wq * 16 + lr)) * HID + h * HD;
        qfrag[0] = *(const bf16x8*)(qrow + lg * 8);
        qfrag[1] = *(const bf16x8*)(qrow + 32 + lg * 8);
    }

    f32x4 acc_o[4];
#pragma unroll
    for (int nt = 0; nt < 4; ++nt) acc_o[nt] = (f32x4){0.f, 0.f, 0.f, 0.f};
    float lsum = 0.f;

    const int  qrow_l = wq * 16 + lr;
    const int* fmrow  = fmat + ((size_t)(b * SEQ) + q0 + qrow_l) * SEQ;

    __syncthreads();

    for (int kt = 0; kt < 8; ++kt) {
        const int k0 = kt * 64;
        {
            const int sk = tid >> 2;
            const int sd = (tid & 3) * 16;
            const ushort* krow = kp + ((size_t)(b * SEQ + k0 + sk)) * HID + h * HD + sd;
            const ushort* vrow = vp + ((size_t)(b * SEQ + k0 + sk)) * HID + h * HD + sd;
            uint4 u0 = *(const uint4*)(krow);
            uint4 u1 = *(const uint4*)(krow + 8);
            *(uint4*)&KT[sk * 72 + sd]     = u0;
            *(uint4*)&KT[sk * 72 + sd + 8] = u1;
            U16x8 a, c;
            a.u[0] = ((const uint4*)vrow)->x; a.u[1] = ((const uint4*)vrow)->y;
            a.u[2] = ((const uint4*)vrow)->z; a.u[3] = ((const uint4*)vrow)->w;
            uint4 v1 = *(const uint4*)(vrow + 8);
            c.u[0] = v1.x; c.u[1] = v1.y; c.u[2] = v1.z; c.u[3] = v1.w;
#pragma unroll
            for (int i2 = 0; i2 < 8; ++i2) {
                VT[(sd + i2) * 72 + sk]     = a.s[i2];
                VT[(sd + 8 + i2) * 72 + sk] = c.s[i2];
            }
        }
        __syncthreads();

#pragma unroll
        for (int mt = 0; mt < 4; ++mt) {
            bf16x8 ka0 = *(const bf16x8*)&KT[(mt * 16 + lr) * 72 + lg * 8];
            bf16x8 ka1 = *(const bf16x8*)&KT[(mt * 16 + lr) * 72 + 32 + lg * 8];
            f32x4 st = (f32x4){0.f, 0.f, 0.f, 0.f};
            st = __builtin_amdgcn_mfma_f32_16x16x32_bf16(ka0, qfrag[0], st, 0, 0, 0);
            st = __builtin_amdgcn_mfma_f32_16x16x32_bf16(ka1, qfrag[1], st, 0, 0, 0);
            const int4 fm4 = *(const int4*)&fmrow[k0 + mt * 16 + lg * 4];
            float pr0 = __expf((st[0] + b2f(qtb[qrow_l * 132 + fm4.x])) * 0.125f);
            float pr1 = __expf((st[1] + b2f(qtb[qrow_l * 132 + fm4.y])) * 0.125f);
            float pr2 = __expf((st[2] + b2f(qtb[qrow_l * 132 + fm4.z])) * 0.125f);
            float pr3 = __expf((st[3] + b2f(qtb[qrow_l * 132 + fm4.w])) * 0.125f);
            lsum += pr0 + pr1 + pr2 + pr3;
            atomicAdd(&sbin[qrow_l * 132 + fm4.x], pr0);
            atomicAdd(&sbin[qrow_l * 132 + fm4.y], pr1);
            atomicAdd(&sbin[qrow_l * 132 + fm4.z], pr2);
            atomicAdd(&sbin[qrow_l * 132 + fm4.w], pr3);
            uint2 pu;
            pu.x = pk(pr0, pr1); pu.y = pk(pr2, pr3);
            *(uint2*)&PL[wq][lr * 72 + mt * 16 + lg * 4] = pu;
        }
        {
            bf16x8 pa0 = *(const bf16x8*)&PL[wq][lr * 72 + lg * 8];
            bf16x8 pa1 = *(const bf16x8*)&PL[wq][lr * 72 + 32 + lg * 8];
#pragma unroll
            for (int nt = 0; nt < 4; ++nt) {
                bf16x8 vb0 = *(const bf16x8*)&VT[(nt * 16 + lr) * 72 + lg * 8];
                bf16x8 vb1 = *(const bf16x8*)&VT[(nt * 16 + lr) * 72 + 32 + lg * 8];
                acc_o[nt] = __builtin_amdgcn_mfma_f32_16x16x32_bf16(pa0, vb0, acc_o[nt], 0, 0, 0);
                acc_o[nt] = __builtin_amdgcn_mfma_f32_16x16x32_bf16(pa1, vb1, acc_o[nt], 0, 0, 0);
            }
        }
        __syncthreads();
    }

    lsum += __shfl_xor(lsum, 16);
    lsum += __shfl_xor(lsum, 32);
    const float invl = 1.f / lsum;
    if (lg == 0) rowinv[wq][lr] = invl;

    float iv[4];
#pragma unroll
    for (int r = 0; r < 4; ++r) iv[r] = rowinv[wq][lg * 4 + r];
#pragma unroll
    for (int nt = 0; nt < 4; ++nt)
#pragma unroll
        for (int r = 0; r < 4; ++r) acc_o[nt][r] *= iv[r];

    {
        const int tt = tid >> 1;
        const int d0 = (tid & 1) * 32;
        const float* tvrow = table_v + (size_t)tt * HD + d0;
#pragma unroll
        for (int i2 = 0; i2 < 32; i2 += 4) {
            float4 a = *(const float4*)(tvrow + i2);
            KVT[(d0 + i2 + 0) * 136 + tt] = f2b(a.x);
            KVT[(d0 + i2 + 1) * 136 + tt] = f2b(a.y);
            KVT[(d0 + i2 + 2) * 136 + tt] = f2b(a.z);
            KVT[(d0 + i2 + 3) * 136 + tt] = f2b(a.w);
        }
    }
    __syncthreads();

#pragma unroll
    for (int ks = 0; ks < 4; ++ks) {
        const float* sp = &sbin[qrow_l * 132 + ks * 32 + lg * 8];
        f32x4 s0 = *(const f32x4*)sp;
        f32x4 s1 = *(const f32x4*)(sp + 4);
        bf16x8 af = pack8(s0[0]*invl, s0[1]*invl, s0[2]*invl, s0[3]*invl,
                          s1[0]*invl, s1[1]*invl, s1[2]*invl, s1[3]*invl);
#pragma unroll
        for (int nt = 0; nt < 4; ++nt) {
            bf16x8 bf_ = *(const bf16x8*)&KVT[(nt * 16 + lr) * 136 + ks * 32 + lg * 8];
            acc_o[nt] = __builtin_amdgcn_mfma_f32_16x16x32_bf16(af, bf_, acc_o[nt], 0, 0, 0);
        }
    }
    {
        float nb[4];
#pragma unroll
        for (int r = 0; r < 4; ++r)
            nb[r] = sbin[(wq * 16 + lg * 4 + r) * 132 + 128] * iv[r];
#pragma unroll
        for (int nt = 0; nt < 4; ++nt) {
            float tv = table_v[(size_t)128 * HD + nt * 16 + lr];
#pragma unroll
            for (int r = 0; r < 4; ++r)
                acc_o[nt][r] = fmaf(nb[r], tv, acc_o[nt][r]);
        }
    }

    {
        ushort* orow = x + ((size_t)(b * SEQ + q0 + wq * 16 + lg * 4)) * HID + h * HD;
#pragma unroll
        for (int r = 0; r < 4; ++r)
#pragma unroll
            for (int nt = 0; nt < 4; ++nt)
                orow[(size_t)r * HID + nt * 16 + lr] = f2b(acc_o[nt][r]);
    }
}

// ---------------------------------------------------------------------------
extern "C" void kernel_launch(void* const* d_in, const int* in_sizes, int n_in,
                              void* d_out, int out_size, void* d_ws, size_t ws_size,
                              hipStream_t stream) {
    const float* query = (const float*)d_in[0];
    const float* key   = (const float*)d_in[1];
    const float* value = (const float*)d_in[2];
    const int*   fmat  = (const int*)d_in[3];
    const float* Wq = (const float*)d_in[4];
    const float* bq = (const float*)d_in[5];
    const float* Wk = (const float*)d_in[6];
    const float* bk = (const float*)d_in[7];
    const float* Wv = (const float*)d_in[8];
    const float* bv = (const float*)d_in[9];
    const float* Wo = (const float*)d_in[10];
    const float* bo = (const float*)d_in[11];
    const float* table_k = (const float*)d_in[12];
    const float* table_v = (const float*)d_in[13];

    const size_t nBLD = (size_t)BATCH * SEQ * HID;   // 4,194,304
    const size_t nW   = (size_t)HID * HID;           // 1,048,576
    ushort* us = (ushort*)d_ws;
    ushort* qin16 = us;                 us += nBLD;
    ushort* kin16 = us;                 us += nBLD;
    ushort* vin16 = us;                 us += nBLD;
    ushort* wq16  = us;                 us += nW;
    ushort* wk16  = us;                 us += nW;
    ushort* wv16  = us;                 us += nW;
    ushort* wo16  = us;                 us += nW;
    ushort* qb16  = us;                 us += nBLD;
    ushort* kb16  = us;                 us += nBLD;
    ushort* vb16  = us;                 us += nBLD;
    ushort* qt16  = us;                 us += (size_t)BATCH * HEADS * SEQ * TAB;
    ushort* xb16  = us;                 us += nBLD;

    // 1) convert inputs + weights to bf16
    ConvArgs ca;
    ca.src[0] = query; ca.src[1] = key; ca.src[2] = value;
    ca.src[3] = Wq; ca.src[4] = Wk; ca.src[5] = Wv; ca.src[6] = Wo;
    ca.dst[0] = qin16; ca.dst[1] = kin16; ca.dst[2] = vin16;
    ca.dst[3] = wq16; ca.dst[4] = wk16; ca.dst[5] = wv16; ca.dst[6] = wo16;
    convert_bf16<<<dim3(8192), 256, 0, stream>>>(ca);

    const int M = BATCH * SEQ;  // 4096

    // 2) QKV projections (batched z=3), bf16 out
    GemmArgs gq = {};
    gq.A[0] = qin16; gq.A[1] = kin16; gq.A[2] = vin16;
    gq.W[0] = wq16;  gq.W[1] = wk16;  gq.W[2] = wv16;
    gq.bias[0] = bq; gq.bias[1] = bk; gq.bias[2] = bv;
    gq.Cf[0] = nullptr; gq.Cf[1] = nullptr; gq.Cf[2] = nullptr;
    gq.Cb[0] = qb16; gq.Cb[1] = kb16; gq.Cb[2] = vb16;
    gemm_bf16<<<dim3(HID / 128, M / 128, 3), 256, 0, stream>>>(gq, M, HID, HID);

    // 3) qtab
    qtab_kernel<<<dim3(SEQ/64, HEADS, BATCH), 256, 0, stream>>>(qb16, table_k, qt16);

    // 4) fused attention
    attn_mfma<<<dim3(BATCH * HEADS * (SEQ/64)), 256, 0, stream>>>(
        qb16, kb16, vb16, qt16, fmat, table_v, xb16);

    // 5) output projection, fp32 out
    GemmArgs go = {};
    go.A[0] = xb16; go.W[0] = wo16; go.bias[0] = bo;
    go.Cf[0] = (float*)d_out; go.Cb[0] = nullptr;
    gemm_bf16<<<dim3(HID / 128, M / 128, 1), 256, 0, stream>>>(go, M, HID, HID);
}

// Round 5
// 339.816 us; speedup vs baseline: 3.8393x; 1.0255x over previous
//
#include <hip/hip_runtime.h>

#define HID 1024
#define HEADS 16
#define HD 64
#define TAB 129
#define QSTR 136   // padded qtab row stride (ushorts, 16B-aligned rows)
#define BATCH 8
#define SEQ 512

typedef unsigned int uint;
typedef unsigned short ushort;
typedef __attribute__((ext_vector_type(4))) float f32x4;
typedef __attribute__((ext_vector_type(8))) __bf16 bf16x8;

// ---------------------------------------------------------------------------
// bf16 helpers
// ---------------------------------------------------------------------------
__device__ __forceinline__ ushort f2b(float x) {
    uint b = __float_as_uint(x);
    uint r = (b + 0x7fffu + ((b >> 16) & 1u)) >> 16;
    return (ushort)r;
}
__device__ __forceinline__ uint pk(float lo, float hi) {
    return (uint)f2b(lo) | ((uint)f2b(hi) << 16);
}
__device__ __forceinline__ float b2f(ushort u) {
    return __uint_as_float(((uint)u) << 16);
}
__device__ __forceinline__ void unpack8(uint4 u, float* f) {
    f[0] = __uint_as_float(u.x << 16); f[1] = __uint_as_float(u.x & 0xffff0000u);
    f[2] = __uint_as_float(u.y << 16); f[3] = __uint_as_float(u.y & 0xffff0000u);
    f[4] = __uint_as_float(u.z << 16); f[5] = __uint_as_float(u.z & 0xffff0000u);
    f[6] = __uint_as_float(u.w << 16); f[7] = __uint_as_float(u.w & 0xffff0000u);
}
union U16x8 { uint u[4]; bf16x8 v; ushort s[8]; };
__device__ __forceinline__ bf16x8 pack8(float a0, float a1, float a2, float a3,
                                        float a4, float a5, float a6, float a7) {
    U16x8 r;
    r.u[0] = pk(a0, a1); r.u[1] = pk(a2, a3);
    r.u[2] = pk(a4, a5); r.u[3] = pk(a6, a7);
    return r.v;
}

#define GL16(gp, lp) __builtin_amdgcn_global_load_lds( \
    (const __attribute__((address_space(1))) void*)(gp), \
    (__attribute__((address_space(3))) void*)(lp), 16, 0, 0)

// ---------------------------------------------------------------------------
// convert fp32 -> bf16: query,key,value (4M each), Wq,Wk,Wv,Wo (1M each)
// ---------------------------------------------------------------------------
struct ConvArgs { const float* src[7]; ushort* dst[7]; };

__global__ __launch_bounds__(256) void convert_bf16(ConvArgs ca) {
    int bid = blockIdx.x;
    int ti, lb;
    if (bid < 6144) { ti = bid >> 11; lb = bid & 2047; }
    else { int r = bid - 6144; ti = 3 + (r >> 9); lb = r & 511; }
    const float* s = ca.src[ti] + (size_t)lb * 2048 + (threadIdx.x << 3);
    ushort*      d = ca.dst[ti] + (size_t)lb * 2048 + (threadIdx.x << 3);
    float4 a = *(const float4*)s;
    float4 c = *(const float4*)(s + 4);
    uint4 u;
    u.x = pk(a.x, a.y); u.y = pk(a.z, a.w);
    u.z = pk(c.x, c.y); u.w = pk(c.z, c.w);
    *(uint4*)d = u;
}

// ---------------------------------------------------------------------------
// bf16 MFMA GEMM (unchanged R4): C_z = A_z @ W_z^T + bias_z
// ---------------------------------------------------------------------------
struct GemmArgs {
    const ushort* A[3];
    const ushort* W[3];
    const float*  bias[3];
    float*        Cf[3];
    ushort*       Cb[3];
};

__global__ __launch_bounds__(256) void gemm_bf16(GemmArgs ga, int M, int N, int K) {
    __shared__ ushort As[2][128 * 32];
    __shared__ ushort Bs[2][128 * 32];
    const int z = blockIdx.z;
    const ushort* A = ga.A[z];
    const ushort* W = ga.W[z];
    const int tid = threadIdx.x;
    const int m0 = blockIdx.y * 128;
    const int n0 = blockIdx.x * 128;

    const int w  = tid >> 6;
    const int l  = tid & 63;
    const int lr = l & 15;
    const int lg = l >> 4;
    const int wm = w >> 1;
    const int wn = w & 1;

    const int sr = tid >> 2;
    const int sc = tid & 3;
    const int g  = sc ^ ((sr >> 1) & 3);
    const ushort* Ag0 = A + (size_t)(m0 + sr)      * K + g * 8;
    const ushort* Ag1 = A + (size_t)(m0 + sr + 64) * K + g * 8;
    const ushort* Wg0 = W + (size_t)(n0 + sr)      * K + g * 8;
    const ushort* Wg1 = W + (size_t)(n0 + sr + 64) * K + g * 8;

    f32x4 acc[4][4];
#pragma unroll
    for (int mt = 0; mt < 4; ++mt)
#pragma unroll
        for (int nt = 0; nt < 4; ++nt) acc[mt][nt] = (f32x4){0.f, 0.f, 0.f, 0.f};

#define STAGE(buf, k0) do { \
        GL16(Ag0 + (k0), &As[buf][w * 512]); \
        GL16(Ag1 + (k0), &As[buf][2048 + w * 512]); \
        GL16(Wg0 + (k0), &Bs[buf][w * 512]); \
        GL16(Wg1 + (k0), &Bs[buf][2048 + w * 512]); \
    } while (0)

    const int swz = (lr >> 1) & 3;
#define COMPUTE(buf) do { \
        bf16x8 af[4], bf[4]; \
        _Pragma("unroll") \
        for (int mt = 0; mt < 4; ++mt) \
            af[mt] = *(const bf16x8*)&As[buf][(wm * 64 + mt * 16 + lr) * 32 + (lg ^ swz) * 8]; \
        _Pragma("unroll") \
        for (int nt = 0; nt < 4; ++nt) \
            bf[nt] = *(const bf16x8*)&Bs[buf][(wn * 64 + nt * 16 + lr) * 32 + (lg ^ swz) * 8]; \
        _Pragma("unroll") \
        for (int mt = 0; mt < 4; ++mt) \
            _Pragma("unroll") \
            for (int nt = 0; nt < 4; ++nt) \
                acc[mt][nt] = __builtin_amdgcn_mfma_f32_16x16x32_bf16(af[mt], bf[nt], acc[mt][nt], 0, 0, 0); \
    } while (0)

    STAGE(0, 0);
    __syncthreads();
    const int nk = K / 32;
    for (int t = 0; t < nk - 1; ++t) {
        STAGE((t + 1) & 1, (size_t)(t + 1) * 32);
        COMPUTE(t & 1);
        __syncthreads();
    }
    COMPUTE((nk - 1) & 1);

    const float* bias = ga.bias[z];
    float bv[4];
#pragma unroll
    for (int nt = 0; nt < 4; ++nt) bv[nt] = bias[n0 + wn * 64 + nt * 16 + lr];
    float*  Cf = ga.Cf[z];
    ushort* Cb = ga.Cb[z];
    if (Cf) {
#pragma unroll
        for (int mt = 0; mt < 4; ++mt)
#pragma unroll
            for (int r4 = 0; r4 < 4; ++r4) {
                size_t m = m0 + wm * 64 + mt * 16 + lg * 4 + r4;
                float* crow = Cf + m * N + n0 + wn * 64 + lr;
#pragma unroll
                for (int nt = 0; nt < 4; ++nt)
                    crow[nt * 16] = acc[mt][nt][r4] + bv[nt];
            }
    } else {
#pragma unroll
        for (int mt = 0; mt < 4; ++mt)
#pragma unroll
            for (int r4 = 0; r4 < 4; ++r4) {
                size_t m = m0 + wm * 64 + mt * 16 + lg * 4 + r4;
                ushort* crow = Cb + m * N + n0 + wn * 64 + lr;
#pragma unroll
                for (int nt = 0; nt < 4; ++nt)
                    crow[nt * 16] = f2b(acc[mt][nt][r4] + bv[nt]);
            }
    }
#undef STAGE
#undef COMPUTE
}

// ---------------------------------------------------------------------------
// qtab[b,h,q,t] = sum_d q4[b,q,h,d] * table_k[t,d]  (bf16 in/out, stride QSTR)
// ---------------------------------------------------------------------------
__global__ __launch_bounds__(256) void qtab_kernel(const ushort* __restrict__ q4,
                                                   const float* __restrict__ table_k,
                                                   ushort* __restrict__ qtab) {
    __shared__ float qs[64][68];
    __shared__ float tk[TAB][68];
    const int tid = threadIdx.x;
    const int q0 = blockIdx.x * 64;
    const int h  = blockIdx.y;
    const int b  = blockIdx.z;
    for (int f = tid; f < 512; f += 256) {
        int r  = f >> 3;
        int dd = (f & 7) << 3;
        uint4 u = *(const uint4*)&q4[((size_t)(b*SEQ + q0 + r)) * HID + h*HD + dd];
        float f8[8];
        unpack8(u, f8);
#pragma unroll
        for (int j = 0; j < 8; ++j) qs[r][dd + j] = f8[j];
    }
    for (int f = tid; f < TAB*16; f += 256) {
        int t  = f >> 4;
        int dd = (f & 15) << 2;
        *(float4*)&tk[t][dd] = *(const float4*)&table_k[t*HD + dd];
    }
    __syncthreads();
    const int tq = tid >> 2;
    const int tg = tid & 3;
    ushort* outrow = qtab + ((size_t)(b*HEADS + h) * SEQ + q0 + tq) * QSTR;
    for (int t = tg; t < TAB; t += 4) {
        float s = 0.f;
#pragma unroll
        for (int d = 0; d < HD; d += 4) {
            float4 qa = *(const float4*)&qs[tq][d];
            float4 ta = *(const float4*)&tk[t][d];
            s = fmaf(qa.x, ta.x, s); s = fmaf(qa.y, ta.y, s);
            s = fmaf(qa.z, ta.z, s); s = fmaf(qa.w, ta.w, s);
        }
        outrow[t] = f2b(s);
    }
}

// ---------------------------------------------------------------------------
// Fused attention v4 (MFMA + swizzled LDS + prefetch):
// one block = (b, h, 64 q-rows), 256 thr, ~75.3 KB LDS, 2 blocks/CU.
//  KT: [k=64][d-granules swz by k&7], staged via global_load_lds (pre-swz src)
//  VT: [d=64][k-granules swz by (d&7)^(((d>>4)&3)<<1)], scalar transpose writes
//      conflict-free; b128 reads conflict-free.
//  V + fm prefetched to registers one tile ahead; mid-tile barrier is
//  lgkmcnt-only so prefetched VMEM stays in flight.
// ---------------------------------------------------------------------------
__global__ __launch_bounds__(256) void attn_mfma(const ushort* __restrict__ qp,
                                                 const ushort* __restrict__ kp,
                                                 const ushort* __restrict__ vp,
                                                 const ushort* __restrict__ qt,
                                                 const int* __restrict__ fmat,
                                                 const float* __restrict__ table_v,
                                                 ushort* __restrict__ x) {
    __shared__ __align__(16) ushort KVT[8192];       // KT[0..4095], VT[4096..8191]; tvT overlay [64][128]
    __shared__ __align__(16) ushort qtb[64 * QSTR];  // 17,408 B qtab rows (bf16)
    __shared__ __align__(16) float  sbin[64 * 132];  // 33,792 B bins
    __shared__ __align__(16) ushort PL[4][16 * 72];  //  9,216 B per-wave P tile
    __shared__ float  rowinv[64];

    const int tid = threadIdx.x;
    const int wq  = tid >> 6;
    const int l   = tid & 63;
    const int lr  = l & 15;
    const int lg  = l >> 4;

    // XCD-bijective swizzle
    const int wg   = blockIdx.x;
    const int work = (wg & 7) * 128 + (wg >> 3);
    const int h    = work & 15;
    const int qblk = (work >> 4) & 7;
    const int b    = work >> 7;
    const int q0   = qblk * 64;
    const size_t bSEQ = (size_t)b * SEQ;
    const int hHD = h * HD;

    // --- K staging via global_load_lds: slot s = w*64+l -> row s>>3, granule s&7;
    //     LDS granule g holds global d-granule g ^ (row&7).
    const int gr  = wq * 8 + (l >> 3);               // rows 0..31 (and +32)
    const int gg  = (l & 7) ^ (l >> 3);              // pre-swizzled global granule
    const ushort* kgsrc = kp + (bSEQ + gr) * HID + hHD + gg * 8;

#define STAGE_K(k0) do { \
        GL16(kgsrc + (size_t)(k0) * HID,        &KVT[wq * 512]); \
        GL16(kgsrc + (size_t)((k0) + 32) * HID, &KVT[2048 + wq * 512]); \
    } while (0)

    // --- V prefetch registers (thread -> V row sk, d-chunk sd)
    const int sk = tid >> 2;
    const int sd = (tid & 3) * 16;
    const ushort* vsrc = vp + (bSEQ + sk) * HID + hHD + sd;
    uint4 vreg0, vreg1;
#define LOAD_V(k0) do { \
        vreg0 = *(const uint4*)(vsrc + (size_t)(k0) * HID); \
        vreg1 = *(const uint4*)(vsrc + (size_t)(k0) * HID + 8); \
    } while (0)

    // VT transpose-write (conflict-free swizzle)
    const int dgs = (sd >> 4) << 1;
    const int klo = sk & 7;
    const int kg  = sk >> 3;
#define WRITE_VT() do { \
        U16x8 a_, c_; \
        a_.u[0] = vreg0.x; a_.u[1] = vreg0.y; a_.u[2] = vreg0.z; a_.u[3] = vreg0.w; \
        c_.u[0] = vreg1.x; c_.u[1] = vreg1.y; c_.u[2] = vreg1.z; c_.u[3] = vreg1.w; \
        _Pragma("unroll") \
        for (int i2 = 0; i2 < 8; ++i2) { \
            int p_ = klo | (((kg ^ (i2 ^ dgs)) & 7) << 3); \
            KVT[4096 + (sd + i2) * 64 + p_]     = a_.s[i2]; \
            KVT[4096 + (sd + 8 + i2) * 64 + p_] = c_.s[i2]; \
        } \
    } while (0)

    // --- fm prefetch
    const int qrow_l = wq * 16 + lr;
    const int* fmrow = fmat + (bSEQ + q0 + qrow_l) * SEQ;
    int4 fmreg[4];
#define LOAD_FM(k0) do { \
        _Pragma("unroll") \
        for (int mt = 0; mt < 4; ++mt) \
            fmreg[mt] = *(const int4*)&fmrow[(k0) + mt * 16 + lg * 4]; \
    } while (0)

    // ---- prologue: issue all tile-0 prefetches, stage qtb, zero sbin --------
    STAGE_K(0);
    LOAD_V(0);
    LOAD_FM(0);
    {
        const uint4* qsrc_ = (const uint4*)(qt + ((size_t)(b * HEADS + h) * SEQ + q0) * QSTR);
        uint4* qdst_ = (uint4*)qtb;
        for (int i = tid; i < 64 * QSTR / 8; i += 256) qdst_[i] = qsrc_[i];
    }
    for (int i = tid; i < 64 * 132; i += 256) sbin[i] = 0.f;

    bf16x8 qfrag[2];
    {
        const ushort* qrow = qp + (bSEQ + q0 + wq * 16 + lr) * HID + hHD;
        qfrag[0] = *(const bf16x8*)(qrow + lg * 8);
        qfrag[1] = *(const bf16x8*)(qrow + 32 + lg * 8);
    }

    f32x4 acc_o[4];
#pragma unroll
    for (int nt = 0; nt < 4; ++nt) acc_o[nt] = (f32x4){0.f, 0.f, 0.f, 0.f};
    float lsum = 0.f;

    const int gmk = lr & 7;              // KT read swizzle
    const int gk0 = (lg ^ gmk) << 3;
    const int gk1 = ((lg ^ gmk) ^ 4) << 3;

    __syncthreads();                      // tile-0 K staged, qtb/sbin ready

    for (int kt = 0; kt < 8; ++kt) {
        const int kbase = kt * 64;

        WRITE_VT();                       // VT(kt) from prefetched regs
        if (kt < 7) LOAD_V(kbase + 64);   // prefetch V(kt+1)

        // ---- QK^T: ST = Ktile . Q^T ; exp ; bins ; P tile ----
#pragma unroll
        for (int mt = 0; mt < 4; ++mt) {
            const int rr = mt * 16 + lr;
            bf16x8 ka0 = *(const bf16x8*)&KVT[rr * 64 + gk0];
            bf16x8 ka1 = *(const bf16x8*)&KVT[rr * 64 + gk1];
            f32x4 st = (f32x4){0.f, 0.f, 0.f, 0.f};
            st = __builtin_amdgcn_mfma_f32_16x16x32_bf16(ka0, qfrag[0], st, 0, 0, 0);
            st = __builtin_amdgcn_mfma_f32_16x16x32_bf16(ka1, qfrag[1], st, 0, 0, 0);
            const int4 fm4 = fmreg[mt];
            float pr0 = __expf((st[0] + b2f(qtb[qrow_l * QSTR + fm4.x])) * 0.125f);
            float pr1 = __expf((st[1] + b2f(qtb[qrow_l * QSTR + fm4.y])) * 0.125f);
            float pr2 = __expf((st[2] + b2f(qtb[qrow_l * QSTR + fm4.z])) * 0.125f);
            float pr3 = __expf((st[3] + b2f(qtb[qrow_l * QSTR + fm4.w])) * 0.125f);
            lsum += pr0 + pr1 + pr2 + pr3;
            atomicAdd(&sbin[qrow_l * 132 + fm4.x], pr0);
            atomicAdd(&sbin[qrow_l * 132 + fm4.y], pr1);
            atomicAdd(&sbin[qrow_l * 132 + fm4.z], pr2);
            atomicAdd(&sbin[qrow_l * 132 + fm4.w], pr3);
            uint2 pu;
            pu.x = pk(pr0, pr1); pu.y = pk(pr2, pr3);
            *(uint2*)&PL[wq][lr * 72 + mt * 16 + lg * 4] = pu;
        }
        if (kt < 7) LOAD_FM(kbase + 64);  // prefetch fm(kt+1)

        // mid-tile barrier: LDS ordering only (keep prefetched VMEM in flight)
        asm volatile("s_waitcnt lgkmcnt(0)" ::: "memory");
        __builtin_amdgcn_s_barrier();

        if (kt < 7) STAGE_K(kbase + 64);  // async K(kt+1); full PV phase to land

        // ---- PV: O += P . Vtile ----
        {
            bf16x8 pa0 = *(const bf16x8*)&PL[wq][lr * 72 + lg * 8];
            bf16x8 pa1 = *(const bf16x8*)&PL[wq][lr * 72 + 32 + lg * 8];
#pragma unroll
            for (int nt = 0; nt < 4; ++nt) {
                const int gmv = (lr & 7) ^ ((nt << 1) & 7);
                const int gv0 = (lg ^ gmv) << 3;
                const int gv1 = ((lg ^ gmv) ^ 4) << 3;
                bf16x8 vb0 = *(const bf16x8*)&KVT[4096 + (nt * 16 + lr) * 64 + gv0];
                bf16x8 vb1 = *(const bf16x8*)&KVT[4096 + (nt * 16 + lr) * 64 + gv1];
                acc_o[nt] = __builtin_amdgcn_mfma_f32_16x16x32_bf16(pa0, vb0, acc_o[nt], 0, 0, 0);
                acc_o[nt] = __builtin_amdgcn_mfma_f32_16x16x32_bf16(pa1, vb1, acc_o[nt], 0, 0, 0);
            }
        }
        __syncthreads();                  // drains glds; VT(kt) reads done
    }

    // ---- row sums -> 1/l ; normalize w1 part ----
    lsum += __shfl_xor(lsum, 16);
    lsum += __shfl_xor(lsum, 32);
    const float invl = 1.f / lsum;
    if (lg == 0) rowinv[wq * 16 + lr] = invl;

    float iv[4];
#pragma unroll
    for (int r = 0; r < 4; ++r) iv[r] = rowinv[wq * 16 + lg * 4 + r];
#pragma unroll
    for (int nt = 0; nt < 4; ++nt)
#pragma unroll
        for (int r = 0; r < 4; ++r) acc_o[nt][r] *= iv[r];

    // ---- tvT overlay (table_v transposed bf16, t=0..127, stride 128) ----
    {
        const int tt = tid >> 1;
        const int d0 = (tid & 1) * 32;
        const float* tvrow = table_v + (size_t)tt * HD + d0;
#pragma unroll
        for (int i2 = 0; i2 < 32; i2 += 4) {
            float4 a = *(const float4*)(tvrow + i2);
            KVT[(d0 + i2 + 0) * 128 + tt] = f2b(a.x);
            KVT[(d0 + i2 + 1) * 128 + tt] = f2b(a.y);
            KVT[(d0 + i2 + 2) * 128 + tt] = f2b(a.z);
            KVT[(d0 + i2 + 3) * 128 + tt] = f2b(a.w);
        }
    }
    __syncthreads();

    // ---- w2: O += (bins/l) . table_v  (4 MFMA k-steps + t=128 tail) ----
#pragma unroll
    for (int ks = 0; ks < 4; ++ks) {
        const float* sp = &sbin[qrow_l * 132 + ks * 32 + lg * 8];
        f32x4 s0 = *(const f32x4*)sp;
        f32x4 s1 = *(const f32x4*)(sp + 4);
        bf16x8 af = pack8(s0[0]*invl, s0[1]*invl, s0[2]*invl, s0[3]*invl,
                          s1[0]*invl, s1[1]*invl, s1[2]*invl, s1[3]*invl);
#pragma unroll
        for (int nt = 0; nt < 4; ++nt) {
            bf16x8 bf_ = *(const bf16x8*)&KVT[(nt * 16 + lr) * 128 + ks * 32 + lg * 8];
            acc_o[nt] = __builtin_amdgcn_mfma_f32_16x16x32_bf16(af, bf_, acc_o[nt], 0, 0, 0);
        }
    }
    {
        float nb[4];
#pragma unroll
        for (int r = 0; r < 4; ++r)
            nb[r] = sbin[(wq * 16 + lg * 4 + r) * 132 + 128] * iv[r];
#pragma unroll
        for (int nt = 0; nt < 4; ++nt) {
            float tv = table_v[(size_t)128 * HD + nt * 16 + lr];
#pragma unroll
            for (int r = 0; r < 4; ++r)
                acc_o[nt][r] = fmaf(nb[r], tv, acc_o[nt][r]);
        }
    }

    // ---- write x (bf16) ----
    {
        ushort* orow = x + (bSEQ + q0 + wq * 16 + lg * 4) * HID + hHD;
#pragma unroll
        for (int r = 0; r < 4; ++r)
#pragma unroll
            for (int nt = 0; nt < 4; ++nt)
                orow[(size_t)r * HID + nt * 16 + lr] = f2b(acc_o[nt][r]);
    }
#undef STAGE_K
#undef LOAD_V
#undef WRITE_VT
#undef LOAD_FM
}

// ---------------------------------------------------------------------------
extern "C" void kernel_launch(void* const* d_in, const int* in_sizes, int n_in,
                              void* d_out, int out_size, void* d_ws, size_t ws_size,
                              hipStream_t stream) {
    const float* query = (const float*)d_in[0];
    const float* key   = (const float*)d_in[1];
    const float* value = (const float*)d_in[2];
    const int*   fmat  = (const int*)d_in[3];
    const float* Wq = (const float*)d_in[4];
    const float* bq = (const float*)d_in[5];
    const float* Wk = (const float*)d_in[6];
    const float* bk = (const float*)d_in[7];
    const float* Wv = (const float*)d_in[8];
    const float* bv = (const float*)d_in[9];
    const float* Wo = (const float*)d_in[10];
    const float* bo = (const float*)d_in[11];
    const float* table_k = (const float*)d_in[12];
    const float* table_v = (const float*)d_in[13];

    const size_t nBLD = (size_t)BATCH * SEQ * HID;   // 4,194,304
    const size_t nW   = (size_t)HID * HID;           // 1,048,576
    ushort* us = (ushort*)d_ws;
    ushort* qin16 = us;                 us += nBLD;
    ushort* kin16 = us;                 us += nBLD;
    ushort* vin16 = us;                 us += nBLD;
    ushort* wq16  = us;                 us += nW;
    ushort* wk16  = us;                 us += nW;
    ushort* wv16  = us;                 us += nW;
    ushort* wo16  = us;                 us += nW;
    ushort* qb16  = us;                 us += nBLD;
    ushort* kb16  = us;                 us += nBLD;
    ushort* vb16  = us;                 us += nBLD;
    ushort* qt16  = us;                 us += (size_t)BATCH * HEADS * SEQ * QSTR;
    ushort* xb16  = us;                 us += nBLD;

    ConvArgs ca;
    ca.src[0] = query; ca.src[1] = key; ca.src[2] = value;
    ca.src[3] = Wq; ca.src[4] = Wk; ca.src[5] = Wv; ca.src[6] = Wo;
    ca.dst[0] = qin16; ca.dst[1] = kin16; ca.dst[2] = vin16;
    ca.dst[3] = wq16; ca.dst[4] = wk16; ca.dst[5] = wv16; ca.dst[6] = wo16;
    convert_bf16<<<dim3(8192), 256, 0, stream>>>(ca);

    const int M = BATCH * SEQ;  // 4096

    GemmArgs gq = {};
    gq.A[0] = qin16; gq.A[1] = kin16; gq.A[2] = vin16;
    gq.W[0] = wq16;  gq.W[1] = wk16;  gq.W[2] = wv16;
    gq.bias[0] = bq; gq.bias[1] = bk; gq.bias[2] = bv;
    gq.Cf[0] = nullptr; gq.Cf[1] = nullptr; gq.Cf[2] = nullptr;
    gq.Cb[0] = qb16; gq.Cb[1] = kb16; gq.Cb[2] = vb16;
    gemm_bf16<<<dim3(HID / 128, M / 128, 3), 256, 0, stream>>>(gq, M, HID, HID);

    qtab_kernel<<<dim3(SEQ/64, HEADS, BATCH), 256, 0, stream>>>(qb16, table_k, qt16);

    attn_mfma<<<dim3(BATCH * HEADS * (SEQ/64)), 256, 0, stream>>>(
        qb16, kb16, vb16, qt16, fmat, table_v, xb16);

    GemmArgs go = {};
    go.A[0] = xb16; go.W[0] = wo16; go.bias[0] = bo;
    go.Cf[0] = (float*)d_out; go.Cb[0] = nullptr;
    gemm_bf16<<<dim3(HID / 128, M / 128, 1), 256, 0, stream>>>(go, M, HID, HID);
}